// Round 5
// baseline (182.319 us; speedup 1.0000x reference)
//
#include <hip/hip_runtime.h>
#include <math.h>

// Problem constants (B,N,D)=(8,2048,256), S=128, H=512, E=2H+S=1152
#define BB 8
#define NN 2048
#define DD 256
#define SS 128
#define HH 512
#define EE 1152

typedef short bf16x8 __attribute__((ext_vector_type(8)));
typedef float f32x4 __attribute__((ext_vector_type(4)));

__device__ __forceinline__ short f2bf(float f) {
    union { float f; unsigned u; } a; a.f = f;
    unsigned r = a.u + 0x7FFFu + ((a.u >> 16) & 1u);  // RNE
    return (short)(r >> 16);
}
__device__ __forceinline__ float bf2f(short s) {
    union { unsigned u; float f; } a; a.u = ((unsigned)(unsigned short)s) << 16;
    return a.f;
}
// async global->LDS, 16B per lane; lds dest = wave-uniform base + lane*16
__device__ __forceinline__ void gl_lds16(const short* g, short* l) {
    __builtin_amdgcn_global_load_lds(
        (const __attribute__((address_space(1))) void*)g,
        (__attribute__((address_space(3))) void*)l, 16, 0, 0);
}

// ---------------- K1: fused RMS norm + weight prep (one launch) ------------
// blocks [0,4096): rmsnorm x->xn bf16 (4 rows/block, wave-per-row)
// blocks [4096,4384): Wuv (DxE) -> Wuv_t (ExD) bf16, 32x32 LDS tiles
// blocks [4384,4512): Wo (HxD) -> Wo_t (DxH) bf16, 32x32 LDS tiles
__global__ __launch_bounds__(256) void k_pre(
        const float* __restrict__ x, const float* __restrict__ gp,
        short* __restrict__ xn,
        const float* __restrict__ Wuv, const float* __restrict__ Wo,
        short* __restrict__ Wuv_t, short* __restrict__ Wo_t) {
    __shared__ float tile[32][33];
    int bid = blockIdx.x;
    int t = threadIdx.x;
    if (bid < 4096) {
        int wave = t >> 6, lane = t & 63;
        long row = (long)bid * 4 + wave;
        float4 xv = ((const float4*)(x + row * DD))[lane];
        float ss = xv.x*xv.x + xv.y*xv.y + xv.z*xv.z + xv.w*xv.w;
        #pragma unroll
        for (int off = 32; off > 0; off >>= 1) ss += __shfl_down(ss, off);
        ss = __shfl(ss, 0);
        float norm = sqrtf(ss) * 0.0625f;              // ||x|| / sqrt(256)
        float scale = gp[0] / fmaxf(norm, 1e-5f);
        short4 o;
        o.x = f2bf(xv.x * scale); o.y = f2bf(xv.y * scale);
        o.z = f2bf(xv.z * scale); o.w = f2bf(xv.w * scale);
        ((short4*)(xn + row * DD))[lane] = o;
    } else if (bid < 4384) {
        int bid2 = bid - 4096;                // 36 e-tiles x 8 d-tiles
        int et = bid2 % 36, dt = bid2 / 36;
        #pragma unroll
        for (int i = 0; i < 4; i++) {
            int idx = t + i*256, r = idx >> 5, c = idx & 31;
            tile[r][c] = Wuv[(long)(dt*32 + r)*EE + et*32 + c];
        }
        __syncthreads();
        #pragma unroll
        for (int i = 0; i < 4; i++) {
            int idx = t + i*256, r = idx >> 5, c = idx & 31;
            Wuv_t[(long)(et*32 + r)*DD + dt*32 + c] = f2bf(tile[c][r]);
        }
    } else {
        int bid3 = bid - 4384;                // 16 h-tiles x 8 d-tiles
        int ht = bid3 % 16, dt = bid3 / 16;
        #pragma unroll
        for (int i = 0; i < 4; i++) {
            int idx = t + i*256, r = idx >> 5, c = idx & 31;
            tile[r][c] = Wo[(long)(ht*32 + r)*DD + dt*32 + c];
        }
        __syncthreads();
        #pragma unroll
        for (int i = 0; i < 4; i++) {
            int idx = t + i*256, r = idx >> 5, c = idx & 31;
            Wo_t[(long)(dt*32 + r)*HH + ht*32 + c] = f2bf(tile[c][r]);
        }
    }
}

// ---------------- K3: GEMM1 + silu + split epilogue (m97-style) ------------
// 128x128 tile, 4 waves, 4x4 16x16x32 acc/wave, global_load_lds width 16,
// unpadded LDS (required by global_load_lds lane-contiguous dest).
__global__ __launch_bounds__(256) void k_gemm1(
        const short* __restrict__ xn, const short* __restrict__ Wuv_t,
        const float* __restrict__ b_uv,
        const float* __restrict__ gamma, const float* __restrict__ beta,
        short* __restrict__ u, short* __restrict__ v,
        short* __restrict__ q, short* __restrict__ k) {
    __shared__ short As[128*64];
    __shared__ short Bs[128*64];
    int m0 = blockIdx.x * 128, n0 = blockIdx.y * 128;
    int t = threadIdx.x, w = t >> 6, lane = t & 63;
    int wr = w & 1, wc = w >> 1, l16 = lane & 15, quad = lane >> 4;
    int lr = lane >> 3, lc = (lane & 7) * 8;   // staging: 8 rows/wave-issue
    f32x4 acc[4][4] = {};
    for (int k0 = 0; k0 < DD; k0 += 64) {
        __syncthreads();
        #pragma unroll
        for (int i = 0; i < 4; i++) {
            int r0 = i*32 + w*8;
            gl_lds16(&xn[(long)(m0 + r0 + lr)*DD + k0 + lc], &As[r0*64]);
            gl_lds16(&Wuv_t[(long)(n0 + r0 + lr)*DD + k0 + lc], &Bs[r0*64]);
        }
        __syncthreads();
        #pragma unroll
        for (int kk = 0; kk < 2; kk++) {
            bf16x8 a[4], bb[4];
            #pragma unroll
            for (int mt = 0; mt < 4; mt++)
                a[mt] = *(const bf16x8*)&As[(wr*64 + mt*16 + l16)*64 + kk*32 + quad*8];
            #pragma unroll
            for (int nt = 0; nt < 4; nt++)
                bb[nt] = *(const bf16x8*)&Bs[(wc*64 + nt*16 + l16)*64 + kk*32 + quad*8];
            #pragma unroll
            for (int mt = 0; mt < 4; mt++)
                #pragma unroll
                for (int nt = 0; nt < 4; nt++)
                    acc[mt][nt] = __builtin_amdgcn_mfma_f32_16x16x32_bf16(
                        a[mt], bb[nt], acc[mt][nt], 0,0,0);
        }
    }
    #pragma unroll
    for (int mt = 0; mt < 4; mt++)
    #pragma unroll
    for (int nt = 0; nt < 4; nt++)
    #pragma unroll
    for (int r = 0; r < 4; r++) {
        int gm = m0 + wr*64 + mt*16 + quad*4 + r;     // C/D: row=(lane>>4)*4+reg
        int ge = n0 + wc*64 + nt*16 + l16;            //      col=lane&15
        float val = acc[mt][nt][r] + b_uv[ge];
        val = val / (1.0f + __expf(-val));            // silu
        if (ge < HH) {
            u[(long)gm*HH + ge] = f2bf(val);
        } else if (ge < 2*HH) {
            v[(long)gm*HH + (ge - HH)] = f2bf(val);
        } else {
            int si = ge - 2*HH;
            q[(long)gm*SS + si] = f2bf(val * gamma[si]      + beta[si]);
            k[(long)gm*SS + si] = f2bf(val * gamma[SS + si] + beta[SS + si]);
        }
    }
}

// ---------------- K4: v -> MFMA B-fragment layout --------------------------
// vfrag[b][mt][ht][lane][e]; lane=quad*16+l16 holds v[b][mt*32+quad*8+e][ht*16+l16]
__global__ __launch_bounds__(256) void k_vfrag(
        const short* __restrict__ v, short* __restrict__ vfrag) {
    __shared__ short tile[32][520];   // 32 m-rows x 512 h (+8 pad)
    int mt = blockIdx.x, b = blockIdx.y;
    int t = threadIdx.x;
    const short* vb = v + ((long)b * NN + mt * 32) * HH;
    #pragma unroll
    for (int i = 0; i < 8; i++) {
        int c = t + i * 256, r = c >> 6, co = (c & 63) * 8;
        *(bf16x8*)&tile[r][co] = *(const bf16x8*)&vb[(long)r * HH + co];
    }
    __syncthreads();
    short* dstb = vfrag + (((long)b * 64 + mt) * 32) * 512;
    #pragma unroll
    for (int i = 0; i < 8; i++) {
        int c = t + i * 256, ht = c >> 6, l = c & 63;
        int quad = l >> 4, l16 = l & 15;
        bf16x8 o;
        #pragma unroll
        for (int e = 0; e < 8; e++) o[e] = tile[quad*8 + e][ht*16 + l16];
        *(bf16x8*)&dstb[(long)ht * 512 + l * 8] = o;
    }
}

// ---------------- K5: fused relu^2 attention + u-gate (v5) -----------------
// v4 post-mortem: 1 barrier/iter still drains vmcnt(0) with in-flight loads
// issued same iter -> ~1000cyc/iter exposed latency, 1 block/CU can't hide.
// v5: unroll 2 m-tiles per barrier; k loads 2 super-iters deep, vf loads 1
// super-iter deep (everything outstanding at a barrier was issued >=1 full
// super-iter earlier -> drain ~free). LDS floor unchanged ~900cyc/m-tile.
__global__ __launch_bounds__(512, 2) void k_attn(
        const short* __restrict__ q, const short* __restrict__ k,
        const short* __restrict__ vfrag, const short* __restrict__ u,
        short* __restrict__ gated) {
    __shared__ short ks[2][2][32][136];  // [parity][tile][m-row][s] (+8 pad)
    __shared__ short Ps[2][2][64][40];   // [parity][tile][q][m] (+8 pad)
    int b = blockIdx.x & 7;                  // batch -> XCD pin
    int i0 = (blockIdx.x >> 3) * 64;
    int t = threadIdx.x, w = t >> 6, lane = t & 63;
    int l16 = lane & 15, quad = lane >> 4;
    int qt = w >> 1, mt = w & 1;             // QK tile assignment
    const short* qb  = q + ((long)b * NN + i0) * SS;
    const short* kb  = k + (long)b * NN * SS;
    const short* vfb = vfrag + (long)b * 64 * 32 * 512;
    const float RS = 0.08838834764831845f;   // 1/sqrt(128)

    int krow = t >> 4, kch = (t & 15) * 8;   // k staging map: 32 rows x 256B

    // hoist q B-frags for this wave's q-tile: B[n=q=l16][k=s]
    bf16x8 qf[4];
    #pragma unroll
    for (int kc = 0; kc < 4; kc++)
        qf[kc] = *(const bf16x8*)&qb[(long)(qt*16 + l16)*SS + kc*32 + quad*8];

    // prologue: stage super-iter 0 (m-tiles 0,1); preload s=1 k + s=0 vf
    *(bf16x8*)&ks[0][0][krow][kch] = *(const bf16x8*)&kb[(long)krow*SS + kch];
    *(bf16x8*)&ks[0][1][krow][kch] = *(const bf16x8*)&kb[(long)(32 + krow)*SS + kch];
    bf16x8 kpre0 = *(const bf16x8*)&kb[(long)(64 + krow)*SS + kch];
    bf16x8 kpre1 = *(const bf16x8*)&kb[(long)(96 + krow)*SS + kch];
    bf16x8 vfc[8];
    #pragma unroll
    for (int jj = 0; jj < 4; jj++) {
        vfc[jj]     = *(const bf16x8*)&vfb[((long)(w*4 + jj))*512 + lane*8];
        vfc[4 + jj] = *(const bf16x8*)&vfb[((long)(32 + w*4 + jj))*512 + lane*8];
    }
    __syncthreads();

    f32x4 acc[16] = {};
    for (int s = 0; s < 32; s++) {
        int p = s & 1;
        // deep prefetch: k for super-iter s+2, vf for s+1 (clamped at tail)
        int sk = (s + 2 < 32) ? s + 2 : s;
        bf16x8 kfar0 = *(const bf16x8*)&kb[(long)(sk*64 + krow)*SS + kch];
        bf16x8 kfar1 = *(const bf16x8*)&kb[(long)(sk*64 + 32 + krow)*SS + kch];
        int sv = (s + 1 < 32) ? s + 1 : s;
        bf16x8 vfn[8];
        #pragma unroll
        for (int jj = 0; jj < 4; jj++) {
            vfn[jj]     = *(const bf16x8*)&vfb[((long)(2*sv)*32     + w*4 + jj)*512 + lane*8];
            vfn[4 + jj] = *(const bf16x8*)&vfb[((long)(2*sv + 1)*32 + w*4 + jj)*512 + lane*8];
        }
        // QK both tiles: S^T (16m x 16q), A = k-frags LDS, B = q-frags regs
        f32x4 scA = {}, scB = {};
        #pragma unroll
        for (int kc = 0; kc < 4; kc++) {
            bf16x8 kfA = *(const bf16x8*)&ks[p][0][mt*16 + l16][kc*32 + quad*8];
            scA = __builtin_amdgcn_mfma_f32_16x16x32_bf16(kfA, qf[kc], scA, 0,0,0);
        }
        #pragma unroll
        for (int kc = 0; kc < 4; kc++) {
            bf16x8 kfB = *(const bf16x8*)&ks[p][1][mt*16 + l16][kc*32 + quad*8];
            scB = __builtin_amdgcn_mfma_f32_16x16x32_bf16(kfB, qf[kc], scB, 0,0,0);
        }
        short4 pwA, pwB;
        {
            float a0 = fmaxf(scA[0]*RS, 0.f), a1 = fmaxf(scA[1]*RS, 0.f);
            float a2 = fmaxf(scA[2]*RS, 0.f), a3 = fmaxf(scA[3]*RS, 0.f);
            pwA.x = f2bf(a0*a0); pwA.y = f2bf(a1*a1);
            pwA.z = f2bf(a2*a2); pwA.w = f2bf(a3*a3);
            float b0 = fmaxf(scB[0]*RS, 0.f), b1 = fmaxf(scB[1]*RS, 0.f);
            float b2 = fmaxf(scB[2]*RS, 0.f), b3 = fmaxf(scB[3]*RS, 0.f);
            pwB.x = f2bf(b0*b0); pwB.y = f2bf(b1*b1);
            pwB.z = f2bf(b2*b2); pwB.w = f2bf(b3*b3);
        }
        // C-layout: row m = quad*4+r, col q = l16 -> store P[q][m]
        *(short4*)&Ps[p][0][qt*16 + l16][mt*16 + quad*4] = pwA;
        *(short4*)&Ps[p][1][qt*16 + l16][mt*16 + quad*4] = pwB;
        // stage k for super-iter s+1 (loaded at s-1, long since landed)
        *(bf16x8*)&ks[p^1][0][krow][kch] = kpre0;
        *(bf16x8*)&ks[p^1][1][krow][kch] = kpre1;
        kpre0 = kfar0; kpre1 = kfar1;
        __syncthreads();                       // single barrier per 2 m-tiles
        // PV both tiles: A-frags from Ps[p][tile], B = vfc in regs
        #pragma unroll
        for (int qq2 = 0; qq2 < 4; qq2++) {
            bf16x8 afA = *(const bf16x8*)&Ps[p][0][qq2*16 + l16][quad*8];
            #pragma unroll
            for (int jj = 0; jj < 4; jj++)
                acc[qq2*4 + jj] = __builtin_amdgcn_mfma_f32_16x16x32_bf16(
                    afA, vfc[jj], acc[qq2*4 + jj], 0,0,0);
        }
        #pragma unroll
        for (int qq2 = 0; qq2 < 4; qq2++) {
            bf16x8 afB = *(const bf16x8*)&Ps[p][1][qq2*16 + l16][quad*8];
            #pragma unroll
            for (int jj = 0; jj < 4; jj++)
                acc[qq2*4 + jj] = __builtin_amdgcn_mfma_f32_16x16x32_bf16(
                    afB, vfc[4 + jj], acc[qq2*4 + jj], 0,0,0);
        }
        #pragma unroll
        for (int i = 0; i < 8; i++) vfc[i] = vfn[i];
    }

    // epilogue: u-gate. acc C-layout: row q = quad*4+r, col h = l16
    long rowbase = (long)b * NN + i0;
    #pragma unroll
    for (int qq2 = 0; qq2 < 4; qq2++)
    #pragma unroll
    for (int jj = 0; jj < 4; jj++) {
        int gh = (w*4 + jj)*16 + l16;
        #pragma unroll
        for (int r = 0; r < 4; r++) {
            long grow = rowbase + qq2*16 + quad*4 + r;
            float uval = bf2f(u[grow * HH + gh]);
            gated[grow * HH + gh] = f2bf(acc[qq2*4 + jj][r] * uval);
        }
    }
}

// ---------------- K6: GEMM2 + bias -> fp32 out (m97-style) -----------------
__global__ __launch_bounds__(256) void k_gemm2(
        const short* __restrict__ gated, const short* __restrict__ Wo_t,
        const float* __restrict__ b_o, float* __restrict__ out) {
    __shared__ short As[128*64];
    __shared__ short Bs[128*64];
    int m0 = blockIdx.x * 128, n0 = blockIdx.y * 128;
    int t = threadIdx.x, w = t >> 6, lane = t & 63;
    int wr = w & 1, wc = w >> 1, l16 = lane & 15, quad = lane >> 4;
    int lr = lane >> 3, lc = (lane & 7) * 8;
    f32x4 acc[4][4] = {};
    for (int k0 = 0; k0 < HH; k0 += 64) {
        __syncthreads();
        #pragma unroll
        for (int i = 0; i < 4; i++) {
            int r0 = i*32 + w*8;
            gl_lds16(&gated[(long)(m0 + r0 + lr)*HH + k0 + lc], &As[r0*64]);
            gl_lds16(&Wo_t[(long)(n0 + r0 + lr)*HH + k0 + lc], &Bs[r0*64]);
        }
        __syncthreads();
        #pragma unroll
        for (int kk = 0; kk < 2; kk++) {
            bf16x8 a[4], bb[4];
            #pragma unroll
            for (int mt = 0; mt < 4; mt++)
                a[mt] = *(const bf16x8*)&As[(wr*64 + mt*16 + l16)*64 + kk*32 + quad*8];
            #pragma unroll
            for (int nt = 0; nt < 4; nt++)
                bb[nt] = *(const bf16x8*)&Bs[(wc*64 + nt*16 + l16)*64 + kk*32 + quad*8];
            #pragma unroll
            for (int mt = 0; mt < 4; mt++)
                #pragma unroll
                for (int nt = 0; nt < 4; nt++)
                    acc[mt][nt] = __builtin_amdgcn_mfma_f32_16x16x32_bf16(
                        a[mt], bb[nt], acc[mt][nt], 0,0,0);
        }
    }
    #pragma unroll
    for (int mt = 0; mt < 4; mt++)
    #pragma unroll
    for (int nt = 0; nt < 4; nt++)
    #pragma unroll
    for (int r = 0; r < 4; r++) {
        int gm = m0 + wr*64 + mt*16 + quad*4 + r;
        int gd = n0 + wc*64 + nt*16 + l16;
        out[(long)gm*DD + gd] = acc[mt][nt][r] + b_o[gd];
    }
}

extern "C" void kernel_launch(void* const* d_in, const int* in_sizes, int n_in,
                              void* d_out, int out_size, void* d_ws, size_t ws_size,
                              hipStream_t stream) {
    const float* x     = (const float*)d_in[0];
    const float* g     = (const float*)d_in[1];
    const float* Wuv   = (const float*)d_in[2];
    const float* b_uv  = (const float*)d_in[3];
    const float* gamma = (const float*)d_in[4];
    const float* beta  = (const float*)d_in[5];
    const float* Wo    = (const float*)d_in[6];
    const float* b_o   = (const float*)d_in[7];
    float* out = (float*)d_out;

    short* ws    = (short*)d_ws;
    short* xn    = ws;                                  // 16384*256
    short* Wuv_t = xn    + (long)16384 * 256;           // 1152*256
    short* Wo_t  = Wuv_t + (long)1152 * 256;            // 256*512
    short* u     = Wo_t  + (long)256 * 512;             // 16384*512
    short* v     = u     + (long)16384 * 512;           // 16384*512
    short* vfrag = v     + (long)16384 * 512;           // 16384*512 (frag layout)
    short* qq    = vfrag + (long)16384 * 512;           // 16384*128
    short* kk    = qq    + (long)16384 * 128;           // 16384*128
    short* gated = kk    + (long)16384 * 128;           // 16384*512

    k_pre<<<4512, 256, 0, stream>>>(x, g, xn, Wuv, Wo, Wuv_t, Wo_t);
    k_gemm1<<<dim3(128, 9), 256, 0, stream>>>(xn, Wuv_t, b_uv, gamma, beta, u, v, qq, kk);
    k_vfrag<<<dim3(64, 8), 256, 0, stream>>>(v, vfrag);
    k_attn<<<256, 512, 0, stream>>>(qq, kk, vfrag, u, gated);
    k_gemm2<<<dim3(128, 2), 256, 0, stream>>>(gated, Wo_t, b_o, out);
}

// Round 7
// 163.721 us; speedup vs baseline: 1.1136x; 1.1136x over previous
//
#include <hip/hip_runtime.h>
#include <math.h>

// Problem constants (B,N,D)=(8,2048,256), S=128, H=512, E=2H+S=1152
#define BB 8
#define NN 2048
#define DD 256
#define SS 128
#define HH 512
#define EE 1152

typedef short bf16x8 __attribute__((ext_vector_type(8)));
typedef float f32x4 __attribute__((ext_vector_type(4)));

__device__ __forceinline__ short f2bf(float f) {
    union { float f; unsigned u; } a; a.f = f;
    unsigned r = a.u + 0x7FFFu + ((a.u >> 16) & 1u);  // RNE
    return (short)(r >> 16);
}
__device__ __forceinline__ float bf2f(short s) {
    union { unsigned u; float f; } a; a.u = ((unsigned)(unsigned short)s) << 16;
    return a.f;
}
// async global->LDS, 16B per lane; lds dest = wave-uniform base + lane*16
__device__ __forceinline__ void gl_lds16(const short* g, short* l) {
    __builtin_amdgcn_global_load_lds(
        (const __attribute__((address_space(1))) void*)g,
        (__attribute__((address_space(3))) void*)l, 16, 0, 0);
}

// ---------------- K1: fused RMS norm + weight prep (one launch) ------------
// blocks [0,4096): rmsnorm x->xn bf16 (4 rows/block, wave-per-row)
// blocks [4096,4384): Wuv (DxE) -> Wuv_t (ExD) bf16, 32x32 LDS tiles
// blocks [4384,4512): Wo (HxD) -> Wo_t (DxH) bf16, 32x32 LDS tiles
__global__ __launch_bounds__(256) void k_pre(
        const float* __restrict__ x, const float* __restrict__ gp,
        short* __restrict__ xn,
        const float* __restrict__ Wuv, const float* __restrict__ Wo,
        short* __restrict__ Wuv_t, short* __restrict__ Wo_t) {
    __shared__ float tile[32][33];
    int bid = blockIdx.x;
    int t = threadIdx.x;
    if (bid < 4096) {
        int wave = t >> 6, lane = t & 63;
        long row = (long)bid * 4 + wave;
        float4 xv = ((const float4*)(x + row * DD))[lane];
        float ss = xv.x*xv.x + xv.y*xv.y + xv.z*xv.z + xv.w*xv.w;
        #pragma unroll
        for (int off = 32; off > 0; off >>= 1) ss += __shfl_down(ss, off);
        ss = __shfl(ss, 0);
        float norm = sqrtf(ss) * 0.0625f;              // ||x|| / sqrt(256)
        float scale = gp[0] / fmaxf(norm, 1e-5f);
        short4 o;
        o.x = f2bf(xv.x * scale); o.y = f2bf(xv.y * scale);
        o.z = f2bf(xv.z * scale); o.w = f2bf(xv.w * scale);
        ((short4*)(xn + row * DD))[lane] = o;
    } else if (bid < 4384) {
        int bid2 = bid - 4096;                // 36 e-tiles x 8 d-tiles
        int et = bid2 % 36, dt = bid2 / 36;
        #pragma unroll
        for (int i = 0; i < 4; i++) {
            int idx = t + i*256, r = idx >> 5, c = idx & 31;
            tile[r][c] = Wuv[(long)(dt*32 + r)*EE + et*32 + c];
        }
        __syncthreads();
        #pragma unroll
        for (int i = 0; i < 4; i++) {
            int idx = t + i*256, r = idx >> 5, c = idx & 31;
            Wuv_t[(long)(et*32 + r)*DD + dt*32 + c] = f2bf(tile[c][r]);
        }
    } else {
        int bid3 = bid - 4384;                // 16 h-tiles x 8 d-tiles
        int ht = bid3 % 16, dt = bid3 / 16;
        #pragma unroll
        for (int i = 0; i < 4; i++) {
            int idx = t + i*256, r = idx >> 5, c = idx & 31;
            tile[r][c] = Wo[(long)(ht*32 + r)*DD + dt*32 + c];
        }
        __syncthreads();
        #pragma unroll
        for (int i = 0; i < 4; i++) {
            int idx = t + i*256, r = idx >> 5, c = idx & 31;
            Wo_t[(long)(dt*32 + r)*HH + ht*32 + c] = f2bf(tile[c][r]);
        }
    }
}

// ---------------- K3: GEMM1 + silu + split epilogue (m97-style) ------------
// 128x128 tile, 4 waves, 4x4 16x16x32 acc/wave, global_load_lds width 16.
// v-region epilogue writes DIRECTLY in vfrag B-frag layout:
// vfrag[b][mt32][ht][lane=quad_v*16+l16v][e], lane holds v[mt32*32+quad_v*8+e][ht*16+l16v]
__global__ __launch_bounds__(256) void k_gemm1(
        const short* __restrict__ xn, const short* __restrict__ Wuv_t,
        const float* __restrict__ b_uv,
        const float* __restrict__ gamma, const float* __restrict__ beta,
        short* __restrict__ u, short* __restrict__ vfrag,
        short* __restrict__ q, short* __restrict__ k) {
    __shared__ short As[128*64];
    __shared__ short Bs[128*64];
    int m0 = blockIdx.x * 128, n0 = blockIdx.y * 128;
    int t = threadIdx.x, w = t >> 6, lane = t & 63;
    int wr = w & 1, wc = w >> 1, l16 = lane & 15, quad = lane >> 4;
    int lr = lane >> 3, lc = (lane & 7) * 8;   // staging: 8 rows/wave-issue
    f32x4 acc[4][4] = {};
    for (int k0 = 0; k0 < DD; k0 += 64) {
        __syncthreads();
        #pragma unroll
        for (int i = 0; i < 4; i++) {
            int r0 = i*32 + w*8;
            gl_lds16(&xn[(long)(m0 + r0 + lr)*DD + k0 + lc], &As[r0*64]);
            gl_lds16(&Wuv_t[(long)(n0 + r0 + lr)*DD + k0 + lc], &Bs[r0*64]);
        }
        __syncthreads();
        #pragma unroll
        for (int kk = 0; kk < 2; kk++) {
            bf16x8 a[4], bb[4];
            #pragma unroll
            for (int mt = 0; mt < 4; mt++)
                a[mt] = *(const bf16x8*)&As[(wr*64 + mt*16 + l16)*64 + kk*32 + quad*8];
            #pragma unroll
            for (int nt = 0; nt < 4; nt++)
                bb[nt] = *(const bf16x8*)&Bs[(wc*64 + nt*16 + l16)*64 + kk*32 + quad*8];
            #pragma unroll
            for (int mt = 0; mt < 4; mt++)
                #pragma unroll
                for (int nt = 0; nt < 4; nt++)
                    acc[mt][nt] = __builtin_amdgcn_mfma_f32_16x16x32_bf16(
                        a[mt], bb[nt], acc[mt][nt], 0,0,0);
        }
    }
    #pragma unroll
    for (int mt = 0; mt < 4; mt++)
    #pragma unroll
    for (int nt = 0; nt < 4; nt++) {
        int gm0 = m0 + wr*64 + mt*16 + quad*4;        // rows gm0..gm0+3
        int ge  = n0 + wc*64 + nt*16 + l16;
        float val[4];
        #pragma unroll
        for (int r = 0; r < 4; r++) {
            float xv = acc[mt][nt][r] + b_uv[ge];
            val[r] = xv / (1.0f + __expf(-xv));        // silu
        }
        if (ge < HH) {
            #pragma unroll
            for (int r = 0; r < 4; r++)
                u[(long)(gm0 + r)*HH + ge] = f2bf(val[r]);
        } else if (ge < 2*HH) {
            int h = ge - HH;
            // vfrag addr: ((b*64+mt32)*32 + ht)*512 + lane'*8 + e
            long base = (((long)((gm0 >> 11)*64 + ((gm0 & 2047) >> 5)) * 32)
                         + (h >> 4)) * 512
                        + ((((gm0 & 31) >> 3)*16 + (h & 15)) * 8) + (gm0 & 7);
            short4 o;
            o.x = f2bf(val[0]); o.y = f2bf(val[1]);
            o.z = f2bf(val[2]); o.w = f2bf(val[3]);
            *(short4*)&vfrag[base] = o;
        } else {
            int si = ge - 2*HH;
            #pragma unroll
            for (int r = 0; r < 4; r++) {
                q[(long)(gm0 + r)*SS + si] = f2bf(val[r] * gamma[si]      + beta[si]);
                k[(long)(gm0 + r)*SS + si] = f2bf(val[r] * gamma[SS + si] + beta[SS + si]);
            }
        }
    }
}

// ---------------- K5: attention + u-gate + fused GEMM2 (v7) ----------------
// Main loop = v4 exactly (51us proven). Epilogue REBUILT race-proof:
//  - no union: all LDS regions are offsets into ONE dynamic-LDS array
//  - no buffer reuse: two DISJOINT 64x264 gtile halves (h<256 / h>=256)
//  - single write phase (all 8 waves write own h-slice), then pure reads
//  - exactly 2 epilogue barriers: B1 = main-LDS dead -> gtile write (WAR),
//    B2 = write -> read (RAW). Both hazard classes proven in main loop.
// LDS layout (shorts): ks[2][32][136] @0 (8704), Ps[2][64][40] @8704 (5120);
// epilogue overlay: g0[64][264] @0, g1[64][264] @16896. Total 33792 shorts
// = 67584 B (dynamic; 2 blocks/CU = 135KB < 160KB).
#define KS(p,row)  (smem + ((p)*32 + (row))*136)
#define PS(p,row)  (smem + 8704 + ((p)*64 + (row))*40)
#define GT(hf,row) (smem + (hf)*16896 + (row)*264)

__global__ __launch_bounds__(512, 2) void k_attn(
        const short* __restrict__ q, const short* __restrict__ k,
        const short* __restrict__ vfrag, const short* __restrict__ u,
        const short* __restrict__ Wo_t, const float* __restrict__ b_o,
        float* __restrict__ out) {
    extern __shared__ __align__(16) short smem[];
    int b = blockIdx.x & 7;                  // batch -> XCD pin
    int i0 = (blockIdx.x >> 3) * 64;
    int t = threadIdx.x, w = t >> 6, lane = t & 63;
    int l16 = lane & 15, quad = lane >> 4;
    int qt = w >> 1, mt = w & 1;             // QK tile assignment
    const short* qb  = q + ((long)b * NN + i0) * SS;
    const short* kb  = k + (long)b * NN * SS;
    const short* vfb = vfrag + (long)b * 64 * 32 * 512;
    const float RS = 0.08838834764831845f;   // 1/sqrt(128)

    int krow = t >> 4, kch = (t & 15) * 8;   // k staging map: 32 rows x 256B

    // hoist q B-frags for this wave's q-tile: B[n=q=l16][k=s]
    bf16x8 qf[4];
    #pragma unroll
    for (int kc = 0; kc < 4; kc++)
        qf[kc] = *(const bf16x8*)&qb[(long)(qt*16 + l16)*SS + kc*32 + quad*8];

    // prologue: stage k(m0=0) -> ks[0]; preload k(m0=32) -> kpre
    *(bf16x8*)&KS(0,krow)[kch] = *(const bf16x8*)&kb[(long)krow*SS + kch];
    bf16x8 kpre = *(const bf16x8*)&kb[(long)(32 + krow)*SS + kch];
    __syncthreads();

    f32x4 acc[16] = {};
    for (int it = 0; it < NN/32; it++) {
        int p = it & 1;
        int m0 = it * 32;
        // preload k for m0+64 (clamp keeps address valid; value unused at end)
        int mnext = (m0 + 64 < NN) ? m0 + 64 : m0;
        bf16x8 knext = *(const bf16x8*)&kb[(long)(mnext + krow)*SS + kch];
        // this iter's v B-frags: coalesced 1KB global loads (land during QK)
        bf16x8 vf[4];
        #pragma unroll
        for (int jj = 0; jj < 4; jj++)
            vf[jj] = *(const bf16x8*)&vfb[((long)it*32 + (w*4 + jj))*512 + lane*8];
        // QK: S^T tile (16m x 16q), A = k-frags from LDS, B = q-frags in regs
        f32x4 sc = {};
        #pragma unroll
        for (int kc = 0; kc < 4; kc++) {
            bf16x8 kf = *(const bf16x8*)&KS(p, mt*16 + l16)[kc*32 + quad*8];
            sc = __builtin_amdgcn_mfma_f32_16x16x32_bf16(kf, qf[kc], sc, 0,0,0);
        }
        short4 pw;
        {
            float s0 = fmaxf(sc[0]*RS, 0.f), s1 = fmaxf(sc[1]*RS, 0.f);
            float s2 = fmaxf(sc[2]*RS, 0.f), s3 = fmaxf(sc[3]*RS, 0.f);
            pw.x = f2bf(s0*s0); pw.y = f2bf(s1*s1);
            pw.z = f2bf(s2*s2); pw.w = f2bf(s3*s3);
        }
        // C-layout: row m = quad*4+r, col q = l16 -> store P[q][m]
        *(short4*)&PS(p, qt*16 + l16)[mt*16 + quad*4] = pw;
        // stage k(m0+32) into the other buffer (loaded last iter, landed)
        *(bf16x8*)&KS(p^1, krow)[kch] = kpre;
        kpre = knext;
        __syncthreads();                       // single barrier per iter
        // PV: A-frags from Ps[p] (reused over 4 h-tiles), B = vf in regs
        bf16x8 af[4];
        #pragma unroll
        for (int qq2 = 0; qq2 < 4; qq2++)
            af[qq2] = *(const bf16x8*)&PS(p, qq2*16 + l16)[quad*8];
        #pragma unroll
        for (int jj = 0; jj < 4; jj++)
            #pragma unroll
            for (int qq2 = 0; qq2 < 4; qq2++)
                acc[qq2*4 + jj] = __builtin_amdgcn_mfma_f32_16x16x32_bf16(
                    af[qq2], vf[jj], acc[qq2*4 + jj], 0,0,0);
    }

    // ---- fused GEMM2 epilogue: out[64 x 256] = (u .* PV) @ Wo + b_o ----
    // acc C-layout: q = qq2*16+quad*4+r, h = w*64 + jj*16 + l16.
    long rowbase = (long)b * NN + i0;
    __syncthreads();                         // B1: all main-loop LDS ops dead
    {
        int hf = w >> 2;                     // this wave's h-half buffer
        int hbase = (w & 3) * 64;            // col offset within half
        #pragma unroll
        for (int qq2 = 0; qq2 < 4; qq2++)
        #pragma unroll
        for (int jj = 0; jj < 4; jj++) {
            int gh = w*64 + jj*16 + l16;     // global h
            #pragma unroll
            for (int r = 0; r < 4; r++) {
                long grow = rowbase + qq2*16 + quad*4 + r;
                float uval = bf2f(u[grow*HH + gh]);
                GT(hf, qq2*16 + quad*4 + r)[hbase + jj*16 + l16] =
                    f2bf(acc[qq2*4 + jj][r] * uval);
            }
        }
    }
    __syncthreads();                         // B2: writes visible; reads only below
    f32x4 acc2[4][2] = {};
    #pragma unroll
    for (int p = 0; p < 2; p++) {            // h-halves, disjoint buffers
        #pragma unroll
        for (int kc = 0; kc < 8; kc++) {
            bf16x8 A[4], Bf[2];
            #pragma unroll
            for (int mt2 = 0; mt2 < 4; mt2++)
                A[mt2] = *(const bf16x8*)&GT(p, mt2*16 + l16)[kc*32 + quad*8];
            #pragma unroll
            for (int nt = 0; nt < 2; nt++)
                Bf[nt] = *(const bf16x8*)&Wo_t[(long)(w*32 + nt*16 + l16)*HH
                                               + p*256 + kc*32 + quad*8];
            #pragma unroll
            for (int mt2 = 0; mt2 < 4; mt2++)
                #pragma unroll
                for (int nt = 0; nt < 2; nt++)
                    acc2[mt2][nt] = __builtin_amdgcn_mfma_f32_16x16x32_bf16(
                        A[mt2], Bf[nt], acc2[mt2][nt], 0,0,0);
        }
    }
    // store out + bias (fp32)
    #pragma unroll
    for (int mt2 = 0; mt2 < 4; mt2++)
    #pragma unroll
    for (int nt = 0; nt < 2; nt++)
    #pragma unroll
    for (int r = 0; r < 4; r++) {
        long grow = rowbase + mt2*16 + quad*4 + r;
        int gd = w*32 + nt*16 + l16;
        out[grow*DD + gd] = acc2[mt2][nt][r] + b_o[gd];
    }
}

extern "C" void kernel_launch(void* const* d_in, const int* in_sizes, int n_in,
                              void* d_out, int out_size, void* d_ws, size_t ws_size,
                              hipStream_t stream) {
    const float* x     = (const float*)d_in[0];
    const float* g     = (const float*)d_in[1];
    const float* Wuv   = (const float*)d_in[2];
    const float* b_uv  = (const float*)d_in[3];
    const float* gamma = (const float*)d_in[4];
    const float* beta  = (const float*)d_in[5];
    const float* Wo    = (const float*)d_in[6];
    const float* b_o   = (const float*)d_in[7];
    float* out = (float*)d_out;

    short* ws    = (short*)d_ws;
    short* xn    = ws;                                  // 16384*256
    short* Wuv_t = xn    + (long)16384 * 256;           // 1152*256
    short* Wo_t  = Wuv_t + (long)1152 * 256;            // 256*512
    short* u     = Wo_t  + (long)256 * 512;             // 16384*512
    short* vfrag = u     + (long)16384 * 512;           // 16384*512 (frag layout)
    short* qq    = vfrag + (long)16384 * 512;           // 16384*128
    short* kk    = qq    + (long)16384 * 128;           // 16384*128

    k_pre<<<4512, 256, 0, stream>>>(x, g, xn, Wuv, Wo, Wuv_t, Wo_t);
    k_gemm1<<<dim3(128, 9), 256, 0, stream>>>(xn, Wuv_t, b_uv, gamma, beta,
                                              u, vfrag, qq, kk);
    k_attn<<<256, 512, 67584, stream>>>(qq, kk, vfrag, u, Wo_t, b_o, out);
}